// Round 7
// baseline (619.785 us; speedup 1.0000x reference)
//
#include <hip/hip_runtime.h>
#include <hip/hip_bf16.h>
#include <math.h>

// AttentionCritic fused pipeline, round 7:
//  - proj+attn fused into ONE kernel (kvs eliminated): per block, 8 agents x 8 batches;
//    A-fragments held in VGPRs across all (head,t) GEMMs; K/V/sel tiles live in LDS;
//    8x8 attention resolved in-block; values written directly.
//  - critic with fused final, XCD swizzle, single transw (unchanged from round 6).
// A=8, B=8192, S=128, ADIM=16, H=512, HEADS=4, D=128. Output f32.

#define AN 8
#define BNB 8192
#define SN 128
#define ADN 16
#define HN 512
#define NHEADS 4
#define DN 128

typedef __hip_bfloat16 bf16;
typedef unsigned short u16;
typedef __attribute__((ext_vector_type(8))) short bf16x8;
typedef __attribute__((ext_vector_type(4))) float f32x4;

__device__ __forceinline__ float lrelu(float x){ return x > 0.f ? x : 0.01f*x; }
__device__ __forceinline__ float bflo(unsigned u){ return __uint_as_float(u << 16); }
__device__ __forceinline__ float bfhi(unsigned u){ return __uint_as_float(u & 0xffff0000u); }
__device__ __forceinline__ float bf2f(u16 u){ return __uint_as_float((unsigned)u << 16); }
__device__ __forceinline__ u16 f2bf(float v){
  union { bf16 h; u16 s; } cv; cv.h = __float2bfloat16(v); return cv.s;
}
__device__ __forceinline__ unsigned pk2(float a, float b){
  return (unsigned)f2bf(a) | ((unsigned)f2bf(b) << 16);
}
__device__ __forceinline__ ushort4 f4bf(float4 v){
  ushort4 u; u.x=f2bf(v.x); u.y=f2bf(v.y); u.z=f2bf(v.z); u.w=f2bf(v.w); return u;
}

// async global->LDS, 16B per lane; LDS dest is wave-uniform base + lane*16
__device__ __forceinline__ void gload16(const u16* g, u16* l){
  __builtin_amdgcn_global_load_lds(
      (const __attribute__((address_space(1))) unsigned int*)(g),
      (__attribute__((address_space(3))) unsigned int*)(l), 16, 0, 0);
}

// ---------------- prep: bf16-pack sa rows [65536][192] + LN stats + action argmax ------------
__global__ __launch_bounds__(256) void prep_kernel(
    const float* __restrict__ states, const float* __restrict__ actions,
    u16* __restrict__ sa_bf, float2* __restrict__ st_s, float2* __restrict__ st_sa,
    int* __restrict__ aip)
{
  const int lane = threadIdx.x & 63;
  const int r = blockIdx.x*4 + (threadIdx.x >> 6);
  float2 sv = ((const float2*)(states + (size_t)r*SN))[lane];
  float s1 = sv.x + sv.y, q1 = sv.x*sv.x + sv.y*sv.y;
  float2 av = make_float2(0.f, 0.f);
  if (lane < 8) av = ((const float2*)(actions + (size_t)r*ADN))[lane];
  float s2 = s1 + av.x + av.y, q2 = q1 + av.x*av.x + av.y*av.y;
  #pragma unroll
  for (int off=32; off; off>>=1){
    s1 += __shfl_xor(s1,off); q1 += __shfl_xor(q1,off);
    s2 += __shfl_xor(s2,off); q2 += __shfl_xor(q2,off);
  }
  float bv; int bi;
  if (lane < 8){
    if (av.x >= av.y){ bv = av.x; bi = 2*lane; } else { bv = av.y; bi = 2*lane+1; }
  } else { bv = -INFINITY; bi = 999; }
  #pragma unroll
  for (int off=1; off<8; off<<=1){
    float ov = __shfl_xor(bv, off); int oi = __shfl_xor(bi, off);
    if (ov > bv || (ov == bv && oi < bi)){ bv = ov; bi = oi; }
  }
  u16* row = sa_bf + (size_t)r*192;
  ushort2 p; p.x = f2bf(sv.x); p.y = f2bf(sv.y);
  *(ushort2*)(row + 2*lane) = p;
  if (lane < 8){
    ushort2 pa; pa.x = f2bf(av.x); pa.y = f2bf(av.y);
    *(ushort2*)(row + 128 + 2*lane) = pa;
  } else if (lane < 32){
    ushort2 z; z.x = 0; z.y = 0;
    *(ushort2*)(row + 128 + 2*lane) = z;
  }
  if (lane==0){
    float m1 = s1*(1.f/128.f), v1 = fmaxf(q1*(1.f/128.f)-m1*m1, 0.f);
    st_s[r] = make_float2(m1, rsqrtf(v1+1e-5f));
    float m2 = s2*(1.f/144.f), v2 = fmaxf(q2*(1.f/144.f)-m2*m2, 0.f);
    st_sa[r] = make_float2(m2, rsqrtf(v2+1e-5f));
    aip[r] = bi;
  }
}

// ---------------- all weight transposes in one launch: [Z][K][N] f32 -> [Z][N][Kp] bf16 ------
__global__ __launch_bounds__(256) void transw_all_kernel(
    const float* __restrict__ Ws_s, const float* __restrict__ Ws_sa, const float* __restrict__ Wc1,
    const float* __restrict__ Wk, const float* __restrict__ Wv, const float* __restrict__ Wsel,
    u16* __restrict__ Wt_s, u16* __restrict__ Wt_sa, u16* __restrict__ Wt_c1, u16* __restrict__ Wt_p)
{
  __shared__ float t[32][33];
  int id = blockIdx.x;
  const float* in; u16* outp; int K, Kp; size_t zs; int gx;
  const int N = (id < 5376) ? 512 : 128;
  if (id < 512){            in=Ws_s;  outp=Wt_s;            K=128;  Kp=128;  zs=(size_t)512*128;  gx=4;  }
  else if (id < 1280){ id-=512;  in=Ws_sa; outp=Wt_sa;      K=144;  Kp=192;  zs=(size_t)512*192;  gx=6;  }
  else if (id < 5376){ id-=1280; in=Wc1;   outp=Wt_c1;      K=1024; Kp=1024; zs=(size_t)512*1024; gx=32; }
  else if (id < 5632){ id-=5376; in=Wk;    outp=Wt_p;            K=512; Kp=512; zs=(size_t)3*128*512; gx=16; }
  else if (id < 5888){ id-=5632; in=Wv;    outp=Wt_p+128*512;    K=512; Kp=512; zs=(size_t)3*128*512; gx=16; }
  else {               id-=5888; in=Wsel;  outp=Wt_p+2*128*512;  K=512; Kp=512; zs=(size_t)3*128*512; gx=16; }
  const int bx = id % gx; id /= gx;
  const int gy = N >> 5;
  const int by = id % gy;
  const int z  = id / gy;
  const int tx = threadIdx.x, ty = threadIdx.y;
  const int k0 = bx*32, n0 = by*32;
  const float* ip = in + (size_t)z*K*N;
  #pragma unroll
  for (int i=0;i<4;i++){
    int k = k0 + ty*4 + i;
    t[ty*4+i][tx] = (k < K) ? ip[(size_t)k*N + n0 + tx] : 0.f;
  }
  __syncthreads();
  u16* op = outp + (size_t)z*zs;
  #pragma unroll
  for (int i=0;i<4;i++){
    int n = n0 + ty*4 + i;
    op[(size_t)n*Kp + k0 + tx] = f2bf(t[tx][ty*4+i]);
  }
}

// ---------------- column sums from transposed bf16 weights (row-sums, 1 wave/row) ------------
__global__ __launch_bounds__(256) void colsum_bf_kernel(
    const u16* __restrict__ Wt_s, const u16* __restrict__ Wt_sa, const u16* __restrict__ Wt_c1,
    float* __restrict__ cs_s, float* __restrict__ cs_sa, float* __restrict__ cs_c1)
{
  const int lane = threadIdx.x & 63;
  const int row = blockIdx.x*4 + (threadIdx.x >> 6);
  const int which = row >> 12; const int idx = row & 4095;
  const u16* W; int K; float* outp;
  if (which==0){ W = Wt_s;  K = 128;  outp = cs_s;  }
  else if (which==1){ W = Wt_sa; K = 192;  outp = cs_sa; }
  else { W = Wt_c1; K = 1024; outp = cs_c1; }
  const u16* p = W + (size_t)idx*K;
  float s = 0.f;
  for (int c = lane*8; c < K; c += 512){
    uint4 v = *(const uint4*)(p + c);
    const unsigned w4[4] = {v.x, v.y, v.z, v.w};
    #pragma unroll
    for (int t=0;t<4;t++) s += bflo(w4[t]) + bfhi(w4[t]);
  }
  #pragma unroll
  for (int off=32; off; off>>=1) s += __shfl_xor(s,off);
  if (lane==0) outp[idx] = s;
}

// ---------------- MFMA GEMM + LN-fold epilogue; MODE 2 fuses the final q-dot -----------------
// MODE 0: s_enc = lrelu(ln(states)@Ws_s + bs_s)          K=128  A=sa_bf(lda 192)
// MODE 1: sa_enc= lrelu(ln([s|a])@Ws_sa + bs_sa)         K=192  A=sa_bf (zero-padded)
// MODE 2: q    += (lrelu(ln([s_enc|values])@Wc1+bc1)) . Wc2[:,argmax]   K=1024, atomicAdd f32
template<int MODE>
__global__ __launch_bounds__(256) void mfma_enc_kernel(
    const u16* __restrict__ Aa, const u16* __restrict__ Ab,
    const u16* __restrict__ Wt, const float* __restrict__ bias,
    const float2* __restrict__ stats, const float* __restrict__ csum,
    u16* __restrict__ outp,
    const float* __restrict__ Wc2, const float* __restrict__ bc2,
    const int* __restrict__ aip, float* __restrict__ qout)
{
  constexpr int K   = (MODE==0) ? 128 : (MODE==1 ? 192 : 1024);
  constexpr int LDA = (MODE==2) ? 512 : 192;
  constexpr int KP  = K;
  constexpr int SMEMN = (MODE==2) ? 20736 : 17408;   // u16 units
  __shared__ __align__(16) u16 smem[SMEMN];
  u16* As = smem;
  u16* Bs = smem + 8192;
  const int tid = threadIdx.x;
  const int w = tid>>6, lane = tid&63;
  const int wr = w>>1, wc = w&1;
  const int srow = lane>>3, skq = (lane&7)^srow;       // pre-swizzled global k-slot

  // XCD chunk swizzle (nwg % 8 == 0)
  const int nwg = gridDim.x * gridDim.y;
  int id = blockIdx.y * gridDim.x + blockIdx.x;
  int swz = (id & 7) * (nwg >> 3) + (id >> 3);
  const int bx = swz % gridDim.x, by = swz / gridDim.x;

  const int m0 = by*128, n0c = bx*128;
  const int a = by >> 6;
  const u16* Wbase = Wt + (size_t)a*HN*KP;
  const int slotbase = (lane>>4) ^ (lane&7);
  f32x4 acc[4][4] = {};

  float* wc2l = nullptr; int* ail = nullptr;
  if constexpr (MODE==2){
    wc2l = (float*)(smem + 16384);          // [16][128] f32, ai-major
    ail  = (int*)(smem + 16384 + 4096);     // [128]
    for (int e = tid; e < 2048; e += 256){
      const int aidx = e >> 7, col = e & 127;
      wc2l[e] = Wc2[((size_t)a*HN + n0c + col)*ADN + aidx];
    }
    if (tid < 128) ail[tid] = aip[m0 + tid];
  }

  for (int k0 = 0; k0 < K; k0 += 64){
    __syncthreads();
    const u16* asrc; int acol;
    if (MODE==2){ asrc = (k0 < 512) ? Aa : Ab; acol = k0 & 511; }
    else        { asrc = Aa; acol = k0; }
    #pragma unroll
    for (int t=0;t<4;t++){
      const int rr = w*32 + t*8;
      gload16(asrc  + (size_t)(m0  + rr + srow)*LDA + acol + skq*8, As + rr*64);
      gload16(Wbase + (size_t)(n0c + rr + srow)*KP  + k0   + skq*8, Bs + rr*64);
    }
    __syncthreads();
    #pragma unroll
    for (int ks=0; ks<2; ++ks){
      bf16x8 af[4], bv[4];
      const int so = ((slotbase ^ (ks<<2)))*8;
      #pragma unroll
      for (int mi=0;mi<4;mi++) af[mi] = *(const bf16x8*)&As[(wr*64+mi*16+(lane&15))*64 + so];
      #pragma unroll
      for (int ni=0;ni<4;ni++) bv[ni] = *(const bf16x8*)&Bs[(wc*64+ni*16+(lane&15))*64 + so];
      #pragma unroll
      for (int mi=0;mi<4;mi++)
        #pragma unroll
        for (int ni=0;ni<4;ni++)
          acc[mi][ni] = __builtin_amdgcn_mfma_f32_16x16x32_bf16(af[mi], bv[ni], acc[mi][ni], 0, 0, 0);
    }
  }

  __syncthreads();
  float csv[4], biv[4];
  #pragma unroll
  for (int ni=0;ni<4;ni++){
    const int col = n0c + wc*64 + ni*16 + (lane&15);
    csv[ni] = csum[a*HN + col];
    biv[ni] = bias[a*HN + col];
  }

  if constexpr (MODE==2){
    #pragma unroll
    for (int mi=0;mi<4;mi++){
      const int rbase = wr*64 + mi*16 + ((lane>>4)<<2);
      #pragma unroll
      for (int v=0; v<4; ++v){
        const int rl = rbase + v;
        const float2 st = stats[m0 + rl];
        const int aidx = ail[rl];
        float p = 0.f;
        #pragma unroll
        for (int ni=0;ni<4;ni++){
          const int coll = wc*64 + ni*16 + (lane&15);
          const float o = lrelu(st.y*(acc[mi][ni][v] - st.x*csv[ni]) + biv[ni]);
          p = fmaf(o, wc2l[aidx*128 + coll], p);
        }
        p += __shfl_xor(p,1); p += __shfl_xor(p,2);
        p += __shfl_xor(p,4); p += __shfl_xor(p,8);
        if ((lane&15)==0){
          if (n0c==0 && wc==0) p += bc2[a*ADN + aidx];
          atomicAdd(qout + m0 + rl, p);
        }
      }
    }
  } else {
    #pragma unroll
    for (int mi=0;mi<4;mi++){
      const int rl = wr*64 + mi*16 + ((lane>>4)<<2);
      #pragma unroll
      for (int v=0; v<4; ++v){
        const float2 st = stats[m0 + rl + v];
        #pragma unroll
        for (int ni=0;ni<4;ni++){
          const float o = lrelu(st.y*(acc[mi][ni][v] - st.x*csv[ni]) + biv[ni]);
          smem[(rl+v)*136 + wc*64 + ni*16 + (lane&15)] = f2bf(o);
        }
      }
    }
    __syncthreads();
    #pragma unroll
    for (int it=0; it<8; ++it){
      const int rl = it*16 + (tid>>4);
      const int ck = (tid&15)*8;
      const uint4 vv = *(const uint4*)&smem[rl*136 + ck];
      *(uint4*)(outp + (size_t)(m0+rl)*HN + n0c + ck) = vv;
    }
  }
}

// ---------------- fused proj+attn: one block = 8 agents x 8 batches, all heads ---------------
// Per (head, t in {key,val,sel}): GEMM 64x128x512 (A-frags in VGPRs, W staged in LDS),
// result -> swizzled LDS tile. Then 8x8 attention per batch in-wave; values written direct.
__global__ __launch_bounds__(256) void fused_pa_kernel(
    const u16* __restrict__ sa_enc, const u16* __restrict__ Wt_p,
    const float* __restrict__ bsel, u16* __restrict__ values)
{
  __shared__ __align__(16) u16 smem[32768];   // Bst [128][64] | key/val/sel [64][128] each
  u16* Bst  = smem;            // 16 KB
  u16* bufK = smem + 8192;
  u16* bufV = smem + 16384;
  u16* bufS = smem + 24576;
  const int tid = threadIdx.x;
  const int w = tid >> 6, lane = tid & 63;
  const int b0 = blockIdx.x * 8;
  const int srow = lane >> 3, skq = (lane & 7) ^ srow;
  const int slotbase = (lane >> 4) ^ (lane & 7);

  // A-fragments for this wave's 16 tile-rows (rows rr = w*16+tr; agent=rr>>3, b=b0+(rr&7)), K=512
  bf16x8 af[16];
  {
    const int tr = lane & 15;
    const int rr = w*16 + tr;
    const u16* arow = sa_enc + ((size_t)(rr>>3)*BNB + b0 + (rr&7))*HN + (lane>>4)*8;
    #pragma unroll
    for (int kc = 0; kc < 16; ++kc)
      af[kc] = *(const bf16x8*)(arow + kc*32);
  }

  for (int h = 0; h < NHEADS; ++h){
    for (int t = 0; t < 3; ++t){
      const u16* Wb = Wt_p + (size_t)(h*3 + t)*DN*HN;
      f32x4 acc[8] = {};
      #pragma unroll
      for (int kc64 = 0; kc64 < 8; ++kc64){
        __syncthreads();
        #pragma unroll
        for (int tt = 0; tt < 4; ++tt){
          const int rb = w*32 + tt*8;
          gload16(Wb + (size_t)(rb + srow)*HN + kc64*64 + skq*8, Bst + rb*64);
        }
        __syncthreads();
        #pragma unroll
        for (int ks = 0; ks < 2; ++ks){
          const int so = (slotbase ^ (ks << 2)) * 8;
          bf16x8 bv[8];
          #pragma unroll
          for (int ni = 0; ni < 8; ++ni)
            bv[ni] = *(const bf16x8*)&Bst[(ni*16 + (lane & 15))*64 + so];
          #pragma unroll
          for (int ni = 0; ni < 8; ++ni)
            acc[ni] = __builtin_amdgcn_mfma_f32_16x16x32_bf16(af[kc64*2+ks], bv[ni], acc[ni], 0, 0, 0);
        }
      }
      // epilogue -> swizzled LDS tile (xor slot bits with agent bits so attention reads are conflict-free)
      u16* obuf = (t==0) ? bufK : (t==1) ? bufV : bufS;
      float bsl[8];
      if (t == 2){
        #pragma unroll
        for (int ni = 0; ni < 8; ++ni) bsl[ni] = bsel[h*DN + ni*16 + (lane&15)];
      }
      #pragma unroll
      for (int ni = 0; ni < 8; ++ni){
        #pragma unroll
        for (int v = 0; v < 4; ++v){
          const int rr2 = w*16 + ((lane>>4)<<2) + v;
          float o = acc[ni][v];
          if (t == 2) o = lrelu(o + bsl[ni]);
          int idx = rr2*128 + ni*16 + (lane & 15);
          idx ^= ((rr2 >> 3) & 7) << 3;
          obuf[idx] = f2bf(o);
        }
      }
    }
    __syncthreads();   // all three tiles complete

    // attention: wave w handles batches i = w*2, w*2+1
    #pragma unroll
    for (int bb = 0; bb < 2; ++bb){
      const int i = w*2 + bb;
      const int ai = lane >> 3, aj = lane & 7;
      // logits: sel[ai] . key[aj] over d=128
      float dot = 0.f;
      #pragma unroll
      for (int s = 0; s < 16; ++s){
        const int sidx = (ai*8 + i)*128 + ((s ^ ai) & 15)*8;
        const int kidx = (aj*8 + i)*128 + ((s ^ aj) & 15)*8;
        uint4 sv = *(const uint4*)&bufS[sidx];
        uint4 kv = *(const uint4*)&bufK[kidx];
        dot += bflo(sv.x)*bflo(kv.x) + bfhi(sv.x)*bfhi(kv.x);
        dot += bflo(sv.y)*bflo(kv.y) + bfhi(sv.y)*bfhi(kv.y);
        dot += bflo(sv.z)*bflo(kv.z) + bfhi(sv.z)*bfhi(kv.z);
        dot += bflo(sv.w)*bflo(kv.w) + bfhi(sv.w)*bfhi(kv.w);
      }
      float logit = dot * 0.08838834764831845f;   // 1/sqrt(128)
      if (ai == aj) logit = -INFINITY;
      float mx = logit;
      mx = fmaxf(mx, __shfl_xor(mx,1,8));
      mx = fmaxf(mx, __shfl_xor(mx,2,8));
      mx = fmaxf(mx, __shfl_xor(mx,4,8));
      const float e = __expf(logit - mx);
      float ssum = e;
      ssum += __shfl_xor(ssum,1,8);
      ssum += __shfl_xor(ssum,2,8);
      ssum += __shfl_xor(ssum,4,8);
      const float wgt = e / ssum;

      // PV: lane role switches to (ai, d-chunk dc); o[16] = sum_aj w[ai][aj] * val[aj][dc*16..+16]
      const int dc = lane & 7;
      float o[16];
      #pragma unroll
      for (int q = 0; q < 16; ++q) o[q] = 0.f;
      #pragma unroll
      for (int j = 0; j < 8; ++j){
        const float wj = __shfl(wgt, j, 8);
        const int vrow = (j*8 + i)*128;
        const uint4 v0 = *(const uint4*)&bufV[vrow + (((dc*2)   ^ j) & 15)*8];
        const uint4 v1 = *(const uint4*)&bufV[vrow + (((dc*2+1) ^ j) & 15)*8];
        o[0]  += wj*bflo(v0.x); o[1]  += wj*bfhi(v0.x);
        o[2]  += wj*bflo(v0.y); o[3]  += wj*bfhi(v0.y);
        o[4]  += wj*bflo(v0.z); o[5]  += wj*bfhi(v0.z);
        o[6]  += wj*bflo(v0.w); o[7]  += wj*bfhi(v0.w);
        o[8]  += wj*bflo(v1.x); o[9]  += wj*bfhi(v1.x);
        o[10] += wj*bflo(v1.y); o[11] += wj*bfhi(v1.y);
        o[12] += wj*bflo(v1.z); o[13] += wj*bfhi(v1.z);
        o[14] += wj*bflo(v1.w); o[15] += wj*bfhi(v1.w);
      }
      uint4 p0, p1;
      p0.x = pk2(o[0],o[1]);   p0.y = pk2(o[2],o[3]);
      p0.z = pk2(o[4],o[5]);   p0.w = pk2(o[6],o[7]);
      p1.x = pk2(o[8],o[9]);   p1.y = pk2(o[10],o[11]);
      p1.z = pk2(o[12],o[13]); p1.w = pk2(o[14],o[15]);
      u16* dst = values + ((size_t)ai*BNB + b0 + i)*HN + h*DN + dc*16;
      *(uint4*)dst = p0;
      *(uint4*)(dst + 8) = p1;
    }
    __syncthreads();   // attention reads done before next head overwrites tiles
  }
}

// ---------------- per-row stats of cin = concat(s_enc, values) (1024), bf16 inputs -----------
__global__ __launch_bounds__(256) void stats_cin_kernel(
    const u16* __restrict__ s_enc, const u16* __restrict__ values, float2* __restrict__ st)
{
  const int lane = threadIdx.x & 63;
  const int r = blockIdx.x*4 + (threadIdx.x >> 6);
  const uint4* p1 = (const uint4*)(s_enc + (size_t)r*HN);
  const uint4* p2 = (const uint4*)(values + (size_t)r*HN);
  uint4 va = p1[lane];
  uint4 vb = p2[lane];
  float s=0.f, q=0.f;
  const unsigned wa[4] = {va.x, va.y, va.z, va.w};
  const unsigned wb[4] = {vb.x, vb.y, vb.z, vb.w};
  #pragma unroll
  for (int t=0;t<4;t++){
    float f0 = bflo(wa[t]), f1 = bfhi(wa[t]);
    float g0 = bflo(wb[t]), g1 = bfhi(wb[t]);
    s += f0+f1+g0+g1; q += f0*f0+f1*f1+g0*g0+g1*g1;
  }
  #pragma unroll
  for (int off=32; off; off>>=1){ s += __shfl_xor(s,off); q += __shfl_xor(q,off); }
  if (lane==0){
    float m = s*(1.f/1024.f); float v = fmaxf(q*(1.f/1024.f) - m*m, 0.f);
    st[r] = make_float2(m, rsqrtf(v + 1e-5f));
  }
}

extern "C" void kernel_launch(void* const* d_in, const int* in_sizes, int n_in,
                              void* d_out, int out_size, void* d_ws, size_t ws_size,
                              hipStream_t stream)
{
  (void)in_sizes; (void)n_in; (void)ws_size;
  const float* states  = (const float*)d_in[0];
  const float* actions = (const float*)d_in[1];
  const float* Ws_s    = (const float*)d_in[2];
  const float* bs_s    = (const float*)d_in[3];
  const float* Ws_sa   = (const float*)d_in[4];
  const float* bs_sa   = (const float*)d_in[5];
  const float* Wk      = (const float*)d_in[6];
  const float* Wv      = (const float*)d_in[7];
  const float* Wsel    = (const float*)d_in[8];
  const float* bsel    = (const float*)d_in[9];
  const float* Wc1     = (const float*)d_in[10];
  const float* bc1     = (const float*)d_in[11];
  const float* Wc2     = (const float*)d_in[12];
  const float* bc2     = (const float*)d_in[13];
  float* outp = (float*)d_out;

  char* ws = (char*)d_ws;
  size_t off = 0;
  auto alloc = [&](size_t n){ void* p = ws + off; off += (n + 255) & ~(size_t)255; return p; };
  u16*    s_enc  = (u16*)   alloc((size_t)AN*BNB*HN*2);   // 64 MB
  u16*    sa_enc = (u16*)   alloc((size_t)AN*BNB*HN*2);   // 64 MB
  u16*    values = (u16*)   alloc((size_t)AN*BNB*HN*2);   // 64 MB
  u16*    sa_bf  = (u16*)   alloc((size_t)AN*BNB*192*2);  // 24 MB
  u16*    Wt_s   = (u16*)   alloc((size_t)AN*HN*128*2);
  u16*    Wt_sa  = (u16*)   alloc((size_t)AN*HN*192*2);
  u16*    Wt_c1  = (u16*)   alloc((size_t)AN*HN*1024*2);
  u16*    Wt_p   = (u16*)   alloc((size_t)NHEADS*3*DN*HN*2);
  float2* st_s   = (float2*)alloc((size_t)AN*BNB*8);
  float2* st_sa  = (float2*)alloc((size_t)AN*BNB*8);
  float2* st_cin = (float2*)alloc((size_t)AN*BNB*8);
  float*  cs_s   = (float*) alloc((size_t)AN*HN*4);
  float*  cs_sa  = (float*) alloc((size_t)AN*HN*4);
  float*  cs_c1  = (float*) alloc((size_t)AN*HN*4);
  int*    aip    = (int*)   alloc((size_t)AN*BNB*4);

  hipMemsetAsync(d_out, 0, (size_t)out_size*4, stream);
  prep_kernel<<<dim3(AN*BNB/4), 256, 0, stream>>>(states, actions, sa_bf, st_s, st_sa, aip);
  transw_all_kernel<<<dim3(6144), dim3(32,8), 0, stream>>>(
      Ws_s, Ws_sa, Wc1, Wk, Wv, Wsel, Wt_s, Wt_sa, Wt_c1, Wt_p);
  colsum_bf_kernel<<<dim3(3*AN*HN/4), 256, 0, stream>>>(Wt_s, Wt_sa, Wt_c1, cs_s, cs_sa, cs_c1);

  mfma_enc_kernel<1><<<dim3(4,512), 256, 0, stream>>>(sa_bf, nullptr, Wt_sa, bs_sa, st_sa, cs_sa,
                                                      sa_enc, nullptr, nullptr, nullptr, nullptr);
  mfma_enc_kernel<0><<<dim3(4,512), 256, 0, stream>>>(sa_bf, nullptr, Wt_s, bs_s, st_s, cs_s,
                                                      s_enc, nullptr, nullptr, nullptr, nullptr);
  fused_pa_kernel<<<dim3(BNB/8), 256, 0, stream>>>(sa_enc, Wt_p, bsel, values);
  stats_cin_kernel<<<dim3(AN*BNB/4), 256, 0, stream>>>(s_enc, values, st_cin);
  mfma_enc_kernel<2><<<dim3(4,512), 256, 0, stream>>>(s_enc, values, Wt_c1, bc1, st_cin, cs_c1,
                                                      nullptr, Wc2, bc2, aip, outp);
}

// Round 8
// 522.965 us; speedup vs baseline: 1.1851x; 1.1851x over previous
//
#include <hip/hip_runtime.h>
#include <hip/hip_bf16.h>
#include <math.h>

// AttentionCritic fused pipeline, round 8:
//  - round-7 fused_pa REVERTED (occupancy/barrier-bound: MfmaUtil 10%, Occ 12%);
//    back to round-6 per-head proj+attn (4 blocks/CU each).
//  - stats_cin kernel ELIMINATED: (sum,sumsq) accumulated via atomicAdd in enc0 epilogue
//    (s_enc half) and attn epilogue (values half); critic computes mean/rstd itself.
// A=8, B=8192, S=128, ADIM=16, H=512, HEADS=4, D=128. Output f32.

#define AN 8
#define BNB 8192
#define SN 128
#define ADN 16
#define HN 512
#define NHEADS 4
#define DN 128

typedef __hip_bfloat16 bf16;
typedef unsigned short u16;
typedef __attribute__((ext_vector_type(8))) short bf16x8;
typedef __attribute__((ext_vector_type(4))) float f32x4;

__device__ __forceinline__ float lrelu(float x){ return x > 0.f ? x : 0.01f*x; }
__device__ __forceinline__ float bflo(unsigned u){ return __uint_as_float(u << 16); }
__device__ __forceinline__ float bfhi(unsigned u){ return __uint_as_float(u & 0xffff0000u); }
__device__ __forceinline__ float bf2f(u16 u){ return __uint_as_float((unsigned)u << 16); }
__device__ __forceinline__ u16 f2bf(float v){
  union { bf16 h; u16 s; } cv; cv.h = __float2bfloat16(v); return cv.s;
}
__device__ __forceinline__ ushort4 f4bf(float4 v){
  ushort4 u; u.x=f2bf(v.x); u.y=f2bf(v.y); u.z=f2bf(v.z); u.w=f2bf(v.w); return u;
}

// async global->LDS, 16B per lane; LDS dest is wave-uniform base + lane*16
__device__ __forceinline__ void gload16(const u16* g, u16* l){
  __builtin_amdgcn_global_load_lds(
      (const __attribute__((address_space(1))) unsigned int*)(g),
      (__attribute__((address_space(3))) unsigned int*)(l), 16, 0, 0);
}

// ---------------- prep: bf16-pack sa rows [65536][192] + LN stats + action argmax ------------
__global__ __launch_bounds__(256) void prep_kernel(
    const float* __restrict__ states, const float* __restrict__ actions,
    u16* __restrict__ sa_bf, float2* __restrict__ st_s, float2* __restrict__ st_sa,
    int* __restrict__ aip)
{
  const int lane = threadIdx.x & 63;
  const int r = blockIdx.x*4 + (threadIdx.x >> 6);
  float2 sv = ((const float2*)(states + (size_t)r*SN))[lane];
  float s1 = sv.x + sv.y, q1 = sv.x*sv.x + sv.y*sv.y;
  float2 av = make_float2(0.f, 0.f);
  if (lane < 8) av = ((const float2*)(actions + (size_t)r*ADN))[lane];
  float s2 = s1 + av.x + av.y, q2 = q1 + av.x*av.x + av.y*av.y;
  #pragma unroll
  for (int off=32; off; off>>=1){
    s1 += __shfl_xor(s1,off); q1 += __shfl_xor(q1,off);
    s2 += __shfl_xor(s2,off); q2 += __shfl_xor(q2,off);
  }
  float bv; int bi;
  if (lane < 8){
    if (av.x >= av.y){ bv = av.x; bi = 2*lane; } else { bv = av.y; bi = 2*lane+1; }
  } else { bv = -INFINITY; bi = 999; }
  #pragma unroll
  for (int off=1; off<8; off<<=1){
    float ov = __shfl_xor(bv, off); int oi = __shfl_xor(bi, off);
    if (ov > bv || (ov == bv && oi < bi)){ bv = ov; bi = oi; }
  }
  u16* row = sa_bf + (size_t)r*192;
  ushort2 p; p.x = f2bf(sv.x); p.y = f2bf(sv.y);
  *(ushort2*)(row + 2*lane) = p;
  if (lane < 8){
    ushort2 pa; pa.x = f2bf(av.x); pa.y = f2bf(av.y);
    *(ushort2*)(row + 128 + 2*lane) = pa;
  } else if (lane < 32){
    ushort2 z; z.x = 0; z.y = 0;
    *(ushort2*)(row + 128 + 2*lane) = z;
  }
  if (lane==0){
    float m1 = s1*(1.f/128.f), v1 = fmaxf(q1*(1.f/128.f)-m1*m1, 0.f);
    st_s[r] = make_float2(m1, rsqrtf(v1+1e-5f));
    float m2 = s2*(1.f/144.f), v2 = fmaxf(q2*(1.f/144.f)-m2*m2, 0.f);
    st_sa[r] = make_float2(m2, rsqrtf(v2+1e-5f));
    aip[r] = bi;
  }
}

// ---------------- all weight transposes in one launch: [Z][K][N] f32 -> [Z][N][Kp] bf16 ------
__global__ __launch_bounds__(256) void transw_all_kernel(
    const float* __restrict__ Ws_s, const float* __restrict__ Ws_sa, const float* __restrict__ Wc1,
    const float* __restrict__ Wk, const float* __restrict__ Wv, const float* __restrict__ Wsel,
    u16* __restrict__ Wt_s, u16* __restrict__ Wt_sa, u16* __restrict__ Wt_c1, u16* __restrict__ Wt_p)
{
  __shared__ float t[32][33];
  int id = blockIdx.x;
  const float* in; u16* outp; int K, Kp; size_t zs; int gx;
  const int N = (id < 5376) ? 512 : 128;
  if (id < 512){            in=Ws_s;  outp=Wt_s;            K=128;  Kp=128;  zs=(size_t)512*128;  gx=4;  }
  else if (id < 1280){ id-=512;  in=Ws_sa; outp=Wt_sa;      K=144;  Kp=192;  zs=(size_t)512*192;  gx=6;  }
  else if (id < 5376){ id-=1280; in=Wc1;   outp=Wt_c1;      K=1024; Kp=1024; zs=(size_t)512*1024; gx=32; }
  else if (id < 5632){ id-=5376; in=Wk;    outp=Wt_p;            K=512; Kp=512; zs=(size_t)3*128*512; gx=16; }
  else if (id < 5888){ id-=5632; in=Wv;    outp=Wt_p+128*512;    K=512; Kp=512; zs=(size_t)3*128*512; gx=16; }
  else {               id-=5888; in=Wsel;  outp=Wt_p+2*128*512;  K=512; Kp=512; zs=(size_t)3*128*512; gx=16; }
  const int bx = id % gx; id /= gx;
  const int gy = N >> 5;
  const int by = id % gy;
  const int z  = id / gy;
  const int tx = threadIdx.x, ty = threadIdx.y;
  const int k0 = bx*32, n0 = by*32;
  const float* ip = in + (size_t)z*K*N;
  #pragma unroll
  for (int i=0;i<4;i++){
    int k = k0 + ty*4 + i;
    t[ty*4+i][tx] = (k < K) ? ip[(size_t)k*N + n0 + tx] : 0.f;
  }
  __syncthreads();
  u16* op = outp + (size_t)z*zs;
  #pragma unroll
  for (int i=0;i<4;i++){
    int n = n0 + ty*4 + i;
    op[(size_t)n*Kp + k0 + tx] = f2bf(t[tx][ty*4+i]);
  }
}

// ---------------- column sums from transposed bf16 weights (row-sums, 1 wave/row) ------------
__global__ __launch_bounds__(256) void colsum_bf_kernel(
    const u16* __restrict__ Wt_s, const u16* __restrict__ Wt_sa, const u16* __restrict__ Wt_c1,
    float* __restrict__ cs_s, float* __restrict__ cs_sa, float* __restrict__ cs_c1)
{
  const int lane = threadIdx.x & 63;
  const int row = blockIdx.x*4 + (threadIdx.x >> 6);
  const int which = row >> 12; const int idx = row & 4095;
  const u16* W; int K; float* outp;
  if (which==0){ W = Wt_s;  K = 128;  outp = cs_s;  }
  else if (which==1){ W = Wt_sa; K = 192;  outp = cs_sa; }
  else { W = Wt_c1; K = 1024; outp = cs_c1; }
  const u16* p = W + (size_t)idx*K;
  float s = 0.f;
  for (int c = lane*8; c < K; c += 512){
    uint4 v = *(const uint4*)(p + c);
    const unsigned w4[4] = {v.x, v.y, v.z, v.w};
    #pragma unroll
    for (int t=0;t<4;t++) s += bflo(w4[t]) + bfhi(w4[t]);
  }
  #pragma unroll
  for (int off=32; off; off>>=1) s += __shfl_xor(s,off);
  if (lane==0) outp[idx] = s;
}

// ---------------- MFMA GEMM + LN-fold epilogue ------------------------------------------------
// MODE 0: s_enc = lrelu(ln(states)@Ws_s + bs_s)   K=128; also atomic-accumulates cin (sum,sumsq)
// MODE 1: sa_enc= lrelu(ln([s|a])@Ws_sa + bs_sa)  K=192
// MODE 2: q += (lrelu(ln(cin)@Wc1+bc1)) . Wc2[:,argmax]  K=1024; stats arg = raw (sum,sumsq)
template<int MODE>
__global__ __launch_bounds__(256) void mfma_enc_kernel(
    const u16* __restrict__ Aa, const u16* __restrict__ Ab,
    const u16* __restrict__ Wt, const float* __restrict__ bias,
    const float2* __restrict__ stats, const float* __restrict__ csum,
    u16* __restrict__ outp, float2* __restrict__ stacc,
    const float* __restrict__ Wc2, const float* __restrict__ bc2,
    const int* __restrict__ aip, float* __restrict__ qout)
{
  constexpr int K   = (MODE==0) ? 128 : (MODE==1 ? 192 : 1024);
  constexpr int LDA = (MODE==2) ? 512 : 192;
  constexpr int KP  = K;
  constexpr int SMEMN = (MODE==2) ? 20736 : 17408;   // u16 units
  __shared__ __align__(16) u16 smem[SMEMN];
  u16* As = smem;
  u16* Bs = smem + 8192;
  const int tid = threadIdx.x;
  const int w = tid>>6, lane = tid&63;
  const int wr = w>>1, wc = w&1;
  const int srow = lane>>3, skq = (lane&7)^srow;       // pre-swizzled global k-slot

  // XCD chunk swizzle (nwg % 8 == 0)
  const int nwg = gridDim.x * gridDim.y;
  int id = blockIdx.y * gridDim.x + blockIdx.x;
  int swz = (id & 7) * (nwg >> 3) + (id >> 3);
  const int bx = swz % gridDim.x, by = swz / gridDim.x;

  const int m0 = by*128, n0c = bx*128;
  const int a = by >> 6;
  const u16* Wbase = Wt + (size_t)a*HN*KP;
  const int slotbase = (lane>>4) ^ (lane&7);
  f32x4 acc[4][4] = {};

  float* wc2l = nullptr; int* ail = nullptr;
  if constexpr (MODE==2){
    wc2l = (float*)(smem + 16384);          // [16][128] f32, ai-major
    ail  = (int*)(smem + 16384 + 4096);     // [128]
    for (int e = tid; e < 2048; e += 256){
      const int aidx = e >> 7, col = e & 127;
      wc2l[e] = Wc2[((size_t)a*HN + n0c + col)*ADN + aidx];
    }
    if (tid < 128) ail[tid] = aip[m0 + tid];
  }

  for (int k0 = 0; k0 < K; k0 += 64){
    __syncthreads();
    const u16* asrc; int acol;
    if (MODE==2){ asrc = (k0 < 512) ? Aa : Ab; acol = k0 & 511; }
    else        { asrc = Aa; acol = k0; }
    #pragma unroll
    for (int t=0;t<4;t++){
      const int rr = w*32 + t*8;
      gload16(asrc  + (size_t)(m0  + rr + srow)*LDA + acol + skq*8, As + rr*64);
      gload16(Wbase + (size_t)(n0c + rr + srow)*KP  + k0   + skq*8, Bs + rr*64);
    }
    __syncthreads();
    #pragma unroll
    for (int ks=0; ks<2; ++ks){
      bf16x8 af[4], bv[4];
      const int so = ((slotbase ^ (ks<<2)))*8;
      #pragma unroll
      for (int mi=0;mi<4;mi++) af[mi] = *(const bf16x8*)&As[(wr*64+mi*16+(lane&15))*64 + so];
      #pragma unroll
      for (int ni=0;ni<4;ni++) bv[ni] = *(const bf16x8*)&Bs[(wc*64+ni*16+(lane&15))*64 + so];
      #pragma unroll
      for (int mi=0;mi<4;mi++)
        #pragma unroll
        for (int ni=0;ni<4;ni++)
          acc[mi][ni] = __builtin_amdgcn_mfma_f32_16x16x32_bf16(af[mi], bv[ni], acc[mi][ni], 0, 0, 0);
    }
  }

  __syncthreads();
  float csv[4], biv[4];
  #pragma unroll
  for (int ni=0;ni<4;ni++){
    const int col = n0c + wc*64 + ni*16 + (lane&15);
    csv[ni] = csum[a*HN + col];
    biv[ni] = bias[a*HN + col];
  }

  if constexpr (MODE==2){
    // h1 stays in registers; stats arg holds raw (sum, sumsq) of cin rows
    #pragma unroll
    for (int mi=0;mi<4;mi++){
      const int rbase = wr*64 + mi*16 + ((lane>>4)<<2);
      #pragma unroll
      for (int v=0; v<4; ++v){
        const int rl = rbase + v;
        const float2 sq = stats[m0 + rl];
        const float mn = sq.x*(1.f/1024.f);
        const float rstd = rsqrtf(fmaxf(sq.y*(1.f/1024.f) - mn*mn, 0.f) + 1e-5f);
        const int aidx = ail[rl];
        float p = 0.f;
        #pragma unroll
        for (int ni=0;ni<4;ni++){
          const int coll = wc*64 + ni*16 + (lane&15);
          const float o = lrelu(rstd*(acc[mi][ni][v] - mn*csv[ni]) + biv[ni]);
          p = fmaf(o, wc2l[aidx*128 + coll], p);
        }
        p += __shfl_xor(p,1); p += __shfl_xor(p,2);
        p += __shfl_xor(p,4); p += __shfl_xor(p,8);
        if ((lane&15)==0){
          if (n0c==0 && wc==0) p += bc2[a*ADN + aidx];
          atomicAdd(qout + m0 + rl, p);
        }
      }
    }
  } else {
    #pragma unroll
    for (int mi=0;mi<4;mi++){
      const int rl = wr*64 + mi*16 + ((lane>>4)<<2);
      #pragma unroll
      for (int v=0; v<4; ++v){
        const float2 st = stats[m0 + rl + v];
        float rs = 0.f, rq = 0.f;
        #pragma unroll
        for (int ni=0;ni<4;ni++){
          const float o = lrelu(st.y*(acc[mi][ni][v] - st.x*csv[ni]) + biv[ni]);
          smem[(rl+v)*136 + wc*64 + ni*16 + (lane&15)] = f2bf(o);
          rs += o; rq += o*o;
        }
        if constexpr (MODE==0){
          rs += __shfl_xor(rs,1); rq += __shfl_xor(rq,1);
          rs += __shfl_xor(rs,2); rq += __shfl_xor(rq,2);
          rs += __shfl_xor(rs,4); rq += __shfl_xor(rq,4);
          rs += __shfl_xor(rs,8); rq += __shfl_xor(rq,8);
          if ((lane&15)==0){
            float* sa = (float*)(stacc + m0 + rl + v);
            atomicAdd(sa, rs); atomicAdd(sa+1, rq);
          }
        }
      }
    }
    __syncthreads();
    #pragma unroll
    for (int it=0; it<8; ++it){
      const int rl = it*16 + (tid>>4);
      const int ck = (tid&15)*8;
      const uint4 vv = *(const uint4*)&smem[rl*136 + ck];
      *(uint4*)(outp + (size_t)(m0+rl)*HN + n0c + ck) = vv;
    }
  }
}

// ---------------- MFMA proj (one head): N=128 per t-block, K=512 -> kvs[t][b][agent][d] ------
__global__ __launch_bounds__(256) void mfma_proj_kernel(
    const u16* __restrict__ sa_enc, const u16* __restrict__ Wt_p,
    const float* __restrict__ bsel, u16* __restrict__ kvs, int head)
{
  __shared__ __align__(16) u16 smem[17408];
  u16* As = smem;
  u16* Bs = smem + 8192;
  const int tid = threadIdx.x;
  const int w = tid>>6, lane = tid&63;
  const int wr = w>>1, wc = w&1;
  const int srow = lane>>3, skq = (lane&7)^srow;

  const int nwg = gridDim.x * gridDim.y;              // (3, 512) = 1536, %8==0
  int id = blockIdx.y * gridDim.x + blockIdx.x;
  int swz = (id & 7) * (nwg >> 3) + (id >> 3);
  const int t = swz % gridDim.x;
  const int m0 = (swz / gridDim.x) * 128;

  const u16* Wbase = Wt_p + (size_t)(head*3 + t)*DN*HN;
  const int slotbase = (lane>>4) ^ (lane&7);
  f32x4 acc[4][4] = {};

  for (int k0 = 0; k0 < HN; k0 += 64){
    __syncthreads();
    #pragma unroll
    for (int tt=0;tt<4;tt++){
      const int rr = w*32 + tt*8;
      gload16(sa_enc + (size_t)(m0 + rr + srow)*HN + k0 + skq*8, As + rr*64);
      gload16(Wbase  + (size_t)(rr + srow)*HN      + k0 + skq*8, Bs + rr*64);
    }
    __syncthreads();
    #pragma unroll
    for (int ks=0; ks<2; ++ks){
      bf16x8 af[4], bv[4];
      const int so = ((slotbase ^ (ks<<2)))*8;
      #pragma unroll
      for (int mi=0;mi<4;mi++) af[mi] = *(const bf16x8*)&As[(wr*64+mi*16+(lane&15))*64 + so];
      #pragma unroll
      for (int ni=0;ni<4;ni++) bv[ni] = *(const bf16x8*)&Bs[(wc*64+ni*16+(lane&15))*64 + so];
      #pragma unroll
      for (int mi=0;mi<4;mi++)
        #pragma unroll
        for (int ni=0;ni<4;ni++)
          acc[mi][ni] = __builtin_amdgcn_mfma_f32_16x16x32_bf16(af[mi], bv[ni], acc[mi][ni], 0, 0, 0);
    }
  }

  __syncthreads();
  const bool issel = (t == 2);
  float biv[4];
  #pragma unroll
  for (int ni=0;ni<4;ni++){
    const int col = wc*64 + ni*16 + (lane&15);
    biv[ni] = issel ? bsel[head*DN + col] : 0.f;
  }
  #pragma unroll
  for (int mi=0;mi<4;mi++){
    const int rl = wr*64 + mi*16 + ((lane>>4)<<2);
    #pragma unroll
    for (int v=0; v<4; ++v){
      #pragma unroll
      for (int ni=0;ni<4;ni++){
        float o = acc[mi][ni][v] + biv[ni];
        if (issel) o = lrelu(o);
        smem[(rl+v)*136 + wc*64 + ni*16 + (lane&15)] = f2bf(o);
      }
    }
  }
  __syncthreads();
  #pragma unroll
  for (int it=0; it<8; ++it){
    const int rl = it*16 + (tid>>4);
    const int ck = (tid&15)*8;
    const int r = m0 + rl;
    const int ar = r >> 13, b = r & (BNB-1);
    const uint4 vv = *(const uint4*)&smem[rl*136 + ck];
    *(uint4*)(kvs + (((size_t)t*BNB + b)*AN + ar)*DN + ck) = vv;
  }
}

// ---------------- attention for ONE head: one wave per b; accumulates cin stats --------------
__global__ __launch_bounds__(256) void attn_kernel(
    const u16* __restrict__ kvs, u16* __restrict__ values, float2* __restrict__ stacc, int kh)
{
  __shared__ float lds[4][3232];
  const int lane = threadIdx.x & 63;
  const int wv   = threadIdx.x >> 6;
  float* selL = &lds[wv][0];
  float* keyL = &lds[wv][1056];
  float* valL = &lds[wv][2112];
  float* wL   = &lds[wv][3168];
  const int b = blockIdx.x*4 + wv;

  #pragma unroll
  for (int m=0;m<3;m++){
    const int t = (m==0) ? 2 : ((m==1) ? 0 : 1);
    float* dst = (m==0) ? selL : ((m==1) ? keyL : valL);
    const uint2* p = (const uint2*)(kvs + ((size_t)t*BNB + b)*(AN*DN));
    #pragma unroll
    for (int it=0; it<4; it++){
      uint2 u = p[it*64 + lane];
      int e = (it*64 + lane)*4;
      int j = e >> 7, d = e & 127;
      float4 f;
      f.x = bflo(u.x); f.y = bfhi(u.x); f.z = bflo(u.y); f.w = bfhi(u.y);
      *(float4*)&dst[j*132 + d] = f;
    }
  }
  __syncthreads();

  const int i = lane >> 3, j = lane & 7;
  float acc = 0.f;
  #pragma unroll 8
  for (int dq=0; dq<32; dq++){
    const float4 s4 = *(const float4*)&selL[i*132 + dq*4];
    const float4 k4 = *(const float4*)&keyL[j*132 + dq*4];
    acc += s4.x*k4.x + s4.y*k4.y + s4.z*k4.z + s4.w*k4.w;
  }
  float logit = acc * 0.08838834764831845f;
  if (i == j) logit = -INFINITY;
  float mx = logit;
  mx = fmaxf(mx, __shfl_xor(mx,1,8));
  mx = fmaxf(mx, __shfl_xor(mx,2,8));
  mx = fmaxf(mx, __shfl_xor(mx,4,8));
  const float e = __expf(logit - mx);
  float s = e;
  s += __shfl_xor(s,1,8);
  s += __shfl_xor(s,2,8);
  s += __shfl_xor(s,4,8);
  wL[i*8 + j] = e / s;
  __syncthreads();

  const int dq = lane & 7;
  float4 o[4];
  #pragma unroll
  for (int tt=0;tt<4;tt++) o[tt] = make_float4(0.f,0.f,0.f,0.f);
  #pragma unroll
  for (int jj=0;jj<8;jj++){
    const float wj = wL[i*8 + jj];
    #pragma unroll
    for (int tt=0;tt<4;tt++){
      const float4 v4 = *(const float4*)&valL[jj*132 + tt*32 + dq*4];
      o[tt].x += wj*v4.x; o[tt].y += wj*v4.y; o[tt].z += wj*v4.z; o[tt].w += wj*v4.w;
    }
  }
  u16* dst = values + ((size_t)i*BNB + b)*HN + kh*DN;
  #pragma unroll
  for (int tt=0;tt<4;tt++)
    *(ushort4*)(dst + tt*32 + dq*4) = f4bf(o[tt]);

  // cin stats contribution: (sum, sumsq) of this head's 128 values for row (agent i, batch b)
  float rs = 0.f, rq = 0.f;
  #pragma unroll
  for (int tt=0;tt<4;tt++){
    rs += o[tt].x + o[tt].y + o[tt].z + o[tt].w;
    rq += o[tt].x*o[tt].x + o[tt].y*o[tt].y + o[tt].z*o[tt].z + o[tt].w*o[tt].w;
  }
  rs += __shfl_xor(rs,1,8); rq += __shfl_xor(rq,1,8);
  rs += __shfl_xor(rs,2,8); rq += __shfl_xor(rq,2,8);
  rs += __shfl_xor(rs,4,8); rq += __shfl_xor(rq,4,8);
  if (dq == 0){
    float* sa = (float*)(stacc + (size_t)i*BNB + b);
    atomicAdd(sa, rs); atomicAdd(sa + 1, rq);
  }
}

extern "C" void kernel_launch(void* const* d_in, const int* in_sizes, int n_in,
                              void* d_out, int out_size, void* d_ws, size_t ws_size,
                              hipStream_t stream)
{
  (void)in_sizes; (void)n_in; (void)ws_size;
  const float* states  = (const float*)d_in[0];
  const float* actions = (const float*)d_in[1];
  const float* Ws_s    = (const float*)d_in[2];
  const float* bs_s    = (const float*)d_in[3];
  const float* Ws_sa   = (const float*)d_in[4];
  const float* bs_sa   = (const float*)d_in[5];
  const float* Wk      = (const float*)d_in[6];
  const float* Wv      = (const float*)d_in[7];
  const float* Wsel    = (const float*)d_in[8];
  const float* bsel    = (const float*)d_in[9];
  const float* Wc1     = (const float*)d_in[10];
  const float* bc1     = (const float*)d_in[11];
  const float* Wc2     = (const float*)d_in[12];
  const float* bc2     = (const float*)d_in[13];
  float* outp = (float*)d_out;

  char* ws = (char*)d_ws;
  size_t off = 0;
  auto alloc = [&](size_t n){ void* p = ws + off; off += (n + 255) & ~(size_t)255; return p; };
  u16*    slot1  = (u16*)   alloc((size_t)AN*BNB*HN*2);   // 64 MB: kvs during attn loop, s_enc after
  u16*    s_enc  = slot1;
  u16*    kvs    = slot1;                                  // 48 MB <= 64 MB
  u16*    sa_enc = (u16*)   alloc((size_t)AN*BNB*HN*2);   // 64 MB
  u16*    values = (u16*)   alloc((size_t)AN*BNB*HN*2);   // 64 MB
  u16*    sa_bf  = (u16*)   alloc((size_t)AN*BNB*192*2);  // 24 MB
  u16*    Wt_s   = (u16*)   alloc((size_t)AN*HN*128*2);
  u16*    Wt_sa  = (u16*)   alloc((size_t)AN*HN*192*2);
  u16*    Wt_c1  = (u16*)   alloc((size_t)AN*HN*1024*2);
  u16*    Wt_p   = (u16*)   alloc((size_t)NHEADS*3*DN*HN*2);
  float2* st_s   = (float2*)alloc((size_t)AN*BNB*8);
  float2* st_sa  = (float2*)alloc((size_t)AN*BNB*8);
  float2* st_cin = (float2*)alloc((size_t)AN*BNB*8);      // (sum, sumsq) accumulator
  float*  cs_s   = (float*) alloc((size_t)AN*HN*4);
  float*  cs_sa  = (float*) alloc((size_t)AN*HN*4);
  float*  cs_c1  = (float*) alloc((size_t)AN*HN*4);
  int*    aip    = (int*)   alloc((size_t)AN*BNB*4);

  hipMemsetAsync(d_out, 0, (size_t)out_size*4, stream);
  hipMemsetAsync(st_cin, 0, (size_t)AN*BNB*8, stream);
  prep_kernel<<<dim3(AN*BNB/4), 256, 0, stream>>>(states, actions, sa_bf, st_s, st_sa, aip);
  transw_all_kernel<<<dim3(6144), dim3(32,8), 0, stream>>>(
      Ws_s, Ws_sa, Wc1, Wk, Wv, Wsel, Wt_s, Wt_sa, Wt_c1, Wt_p);
  colsum_bf_kernel<<<dim3(3*AN*HN/4), 256, 0, stream>>>(Wt_s, Wt_sa, Wt_c1, cs_s, cs_sa, cs_c1);

  mfma_enc_kernel<1><<<dim3(4,512), 256, 0, stream>>>(sa_bf, nullptr, Wt_sa, bs_sa, st_sa, cs_sa,
                                                      sa_enc, nullptr, nullptr, nullptr, nullptr, nullptr);
  for (int kh = 0; kh < NHEADS; ++kh){
    mfma_proj_kernel<<<dim3(3,512), 256, 0, stream>>>(sa_enc, Wt_p, bsel, kvs, kh);
    attn_kernel<<<dim3(BNB/4), 256, 0, stream>>>(kvs, values, st_cin, kh);
  }
  mfma_enc_kernel<0><<<dim3(4,512), 256, 0, stream>>>(sa_bf, nullptr, Wt_s, bs_s, st_s, cs_s,
                                                      s_enc, st_cin, nullptr, nullptr, nullptr, nullptr);
  mfma_enc_kernel<2><<<dim3(4,512), 256, 0, stream>>>(s_enc, values, Wt_c1, bc1, st_cin, cs_c1,
                                                      nullptr, nullptr, Wc2, bc2, aip, outp);
}

// Round 9
// 460.900 us; speedup vs baseline: 1.3447x; 1.1347x over previous
//
#include <hip/hip_runtime.h>
#include <hip/hip_bf16.h>
#include <math.h>

// AttentionCritic fused pipeline, round 9:
//  - stats fusion REVERTED to round-6 config (round-8 atomics cost ~50us net).
//  - critic rewritten as 256x256 8-phase counted-vmcnt MFMA kernel (T2+T3+T4+T5):
//    2-deep LDS dbuf, per-phase {ds_read || stage-issue || 16 MFMA}, vmcnt(4) per K-tile
//    boundary (never 0 mid-loop), setprio around MFMA clusters, fused final q-dot epilogue.
// A=8, B=8192, S=128, ADIM=16, H=512, HEADS=4, D=128. Output f32.

#define AN 8
#define BNB 8192
#define SN 128
#define ADN 16
#define HN 512
#define NHEADS 4
#define DN 128

typedef __hip_bfloat16 bf16;
typedef unsigned short u16;
typedef __attribute__((ext_vector_type(8))) short bf16x8;
typedef __attribute__((ext_vector_type(4))) float f32x4;

__device__ __forceinline__ float lrelu(float x){ return x > 0.f ? x : 0.01f*x; }
__device__ __forceinline__ float bflo(unsigned u){ return __uint_as_float(u << 16); }
__device__ __forceinline__ float bfhi(unsigned u){ return __uint_as_float(u & 0xffff0000u); }
__device__ __forceinline__ float bf2f(u16 u){ return __uint_as_float((unsigned)u << 16); }
__device__ __forceinline__ u16 f2bf(float v){
  union { bf16 h; u16 s; } cv; cv.h = __float2bfloat16(v); return cv.s;
}
__device__ __forceinline__ ushort4 f4bf(float4 v){
  ushort4 u; u.x=f2bf(v.x); u.y=f2bf(v.y); u.z=f2bf(v.z); u.w=f2bf(v.w); return u;
}

// async global->LDS, 16B per lane; LDS dest is wave-uniform base + lane*16
__device__ __forceinline__ void gload16(const u16* g, u16* l){
  __builtin_amdgcn_global_load_lds(
      (const __attribute__((address_space(1))) unsigned int*)(g),
      (__attribute__((address_space(3))) unsigned int*)(l), 16, 0, 0);
}

// ---------------- prep: bf16-pack sa rows [65536][192] + LN stats + action argmax ------------
__global__ __launch_bounds__(256) void prep_kernel(
    const float* __restrict__ states, const float* __restrict__ actions,
    u16* __restrict__ sa_bf, float2* __restrict__ st_s, float2* __restrict__ st_sa,
    int* __restrict__ aip)
{
  const int lane = threadIdx.x & 63;
  const int r = blockIdx.x*4 + (threadIdx.x >> 6);
  float2 sv = ((const float2*)(states + (size_t)r*SN))[lane];
  float s1 = sv.x + sv.y, q1 = sv.x*sv.x + sv.y*sv.y;
  float2 av = make_float2(0.f, 0.f);
  if (lane < 8) av = ((const float2*)(actions + (size_t)r*ADN))[lane];
  float s2 = s1 + av.x + av.y, q2 = q1 + av.x*av.x + av.y*av.y;
  #pragma unroll
  for (int off=32; off; off>>=1){
    s1 += __shfl_xor(s1,off); q1 += __shfl_xor(q1,off);
    s2 += __shfl_xor(s2,off); q2 += __shfl_xor(q2,off);
  }
  float bv; int bi;
  if (lane < 8){
    if (av.x >= av.y){ bv = av.x; bi = 2*lane; } else { bv = av.y; bi = 2*lane+1; }
  } else { bv = -INFINITY; bi = 999; }
  #pragma unroll
  for (int off=1; off<8; off<<=1){
    float ov = __shfl_xor(bv, off); int oi = __shfl_xor(bi, off);
    if (ov > bv || (ov == bv && oi < bi)){ bv = ov; bi = oi; }
  }
  u16* row = sa_bf + (size_t)r*192;
  ushort2 p; p.x = f2bf(sv.x); p.y = f2bf(sv.y);
  *(ushort2*)(row + 2*lane) = p;
  if (lane < 8){
    ushort2 pa; pa.x = f2bf(av.x); pa.y = f2bf(av.y);
    *(ushort2*)(row + 128 + 2*lane) = pa;
  } else if (lane < 32){
    ushort2 z; z.x = 0; z.y = 0;
    *(ushort2*)(row + 128 + 2*lane) = z;
  }
  if (lane==0){
    float m1 = s1*(1.f/128.f), v1 = fmaxf(q1*(1.f/128.f)-m1*m1, 0.f);
    st_s[r] = make_float2(m1, rsqrtf(v1+1e-5f));
    float m2 = s2*(1.f/144.f), v2 = fmaxf(q2*(1.f/144.f)-m2*m2, 0.f);
    st_sa[r] = make_float2(m2, rsqrtf(v2+1e-5f));
    aip[r] = bi;
  }
}

// ---------------- all weight transposes in one launch: [Z][K][N] f32 -> [Z][N][Kp] bf16 ------
__global__ __launch_bounds__(256) void transw_all_kernel(
    const float* __restrict__ Ws_s, const float* __restrict__ Ws_sa, const float* __restrict__ Wc1,
    const float* __restrict__ Wk, const float* __restrict__ Wv, const float* __restrict__ Wsel,
    u16* __restrict__ Wt_s, u16* __restrict__ Wt_sa, u16* __restrict__ Wt_c1, u16* __restrict__ Wt_p)
{
  __shared__ float t[32][33];
  int id = blockIdx.x;
  const float* in; u16* outp; int K, Kp; size_t zs; int gx;
  const int N = (id < 5376) ? 512 : 128;
  if (id < 512){            in=Ws_s;  outp=Wt_s;            K=128;  Kp=128;  zs=(size_t)512*128;  gx=4;  }
  else if (id < 1280){ id-=512;  in=Ws_sa; outp=Wt_sa;      K=144;  Kp=192;  zs=(size_t)512*192;  gx=6;  }
  else if (id < 5376){ id-=1280; in=Wc1;   outp=Wt_c1;      K=1024; Kp=1024; zs=(size_t)512*1024; gx=32; }
  else if (id < 5632){ id-=5376; in=Wk;    outp=Wt_p;            K=512; Kp=512; zs=(size_t)3*128*512; gx=16; }
  else if (id < 5888){ id-=5632; in=Wv;    outp=Wt_p+128*512;    K=512; Kp=512; zs=(size_t)3*128*512; gx=16; }
  else {               id-=5888; in=Wsel;  outp=Wt_p+2*128*512;  K=512; Kp=512; zs=(size_t)3*128*512; gx=16; }
  const int bx = id % gx; id /= gx;
  const int gy = N >> 5;
  const int by = id % gy;
  const int z  = id / gy;
  const int tx = threadIdx.x, ty = threadIdx.y;
  const int k0 = bx*32, n0 = by*32;
  const float* ip = in + (size_t)z*K*N;
  #pragma unroll
  for (int i=0;i<4;i++){
    int k = k0 + ty*4 + i;
    t[ty*4+i][tx] = (k < K) ? ip[(size_t)k*N + n0 + tx] : 0.f;
  }
  __syncthreads();
  u16* op = outp + (size_t)z*zs;
  #pragma unroll
  for (int i=0;i<4;i++){
    int n = n0 + ty*4 + i;
    op[(size_t)n*Kp + k0 + tx] = f2bf(t[tx][ty*4+i]);
  }
}

// ---------------- column sums from transposed bf16 weights (row-sums, 1 wave/row) ------------
__global__ __launch_bounds__(256) void colsum_bf_kernel(
    const u16* __restrict__ Wt_s, const u16* __restrict__ Wt_sa, const u16* __restrict__ Wt_c1,
    float* __restrict__ cs_s, float* __restrict__ cs_sa, float* __restrict__ cs_c1)
{
  const int lane = threadIdx.x & 63;
  const int row = blockIdx.x*4 + (threadIdx.x >> 6);
  const int which = row >> 12; const int idx = row & 4095;
  const u16* W; int K; float* outp;
  if (which==0){ W = Wt_s;  K = 128;  outp = cs_s;  }
  else if (which==1){ W = Wt_sa; K = 192;  outp = cs_sa; }
  else { W = Wt_c1; K = 1024; outp = cs_c1; }
  const u16* p = W + (size_t)idx*K;
  float s = 0.f;
  for (int c = lane*8; c < K; c += 512){
    uint4 v = *(const uint4*)(p + c);
    const unsigned w4[4] = {v.x, v.y, v.z, v.w};
    #pragma unroll
    for (int t=0;t<4;t++) s += bflo(w4[t]) + bfhi(w4[t]);
  }
  #pragma unroll
  for (int off=32; off; off>>=1) s += __shfl_xor(s,off);
  if (lane==0) outp[idx] = s;
}

// ---------------- MFMA GEMM + LN-fold epilogue (128x128 tile, encoders) ----------------------
// MODE 0: s_enc = lrelu(ln(states)@Ws_s + bs_s)   K=128  A=sa_bf(lda 192)
// MODE 1: sa_enc= lrelu(ln([s|a])@Ws_sa + bs_sa)  K=192
template<int MODE>
__global__ __launch_bounds__(256) void mfma_enc_kernel(
    const u16* __restrict__ Aa,
    const u16* __restrict__ Wt, const float* __restrict__ bias,
    const float2* __restrict__ stats, const float* __restrict__ csum,
    u16* __restrict__ outp)
{
  constexpr int K   = (MODE==0) ? 128 : 192;
  constexpr int LDA = 192;
  constexpr int KP  = K;
  __shared__ __align__(16) u16 smem[17408];
  u16* As = smem;
  u16* Bs = smem + 8192;
  const int tid = threadIdx.x;
  const int w = tid>>6, lane = tid&63;
  const int wr = w>>1, wc = w&1;
  const int srow = lane>>3, skq = (lane&7)^srow;

  const int nwg = gridDim.x * gridDim.y;
  int id = blockIdx.y * gridDim.x + blockIdx.x;
  int swz = (id & 7) * (nwg >> 3) + (id >> 3);
  const int bx = swz % gridDim.x, by = swz / gridDim.x;

  const int m0 = by*128, n0c = bx*128;
  const int a = by >> 6;
  const u16* Wbase = Wt + (size_t)a*HN*KP;
  const int slotbase = (lane>>4) ^ (lane&7);
  f32x4 acc[4][4] = {};

  for (int k0 = 0; k0 < K; k0 += 64){
    __syncthreads();
    #pragma unroll
    for (int t=0;t<4;t++){
      const int rr = w*32 + t*8;
      gload16(Aa    + (size_t)(m0  + rr + srow)*LDA + k0 + skq*8, As + rr*64);
      gload16(Wbase + (size_t)(n0c + rr + srow)*KP  + k0 + skq*8, Bs + rr*64);
    }
    __syncthreads();
    #pragma unroll
    for (int ks=0; ks<2; ++ks){
      bf16x8 af[4], bv[4];
      const int so = ((slotbase ^ (ks<<2)))*8;
      #pragma unroll
      for (int mi=0;mi<4;mi++) af[mi] = *(const bf16x8*)&As[(wr*64+mi*16+(lane&15))*64 + so];
      #pragma unroll
      for (int ni=0;ni<4;ni++) bv[ni] = *(const bf16x8*)&Bs[(wc*64+ni*16+(lane&15))*64 + so];
      #pragma unroll
      for (int mi=0;mi<4;mi++)
        #pragma unroll
        for (int ni=0;ni<4;ni++)
          acc[mi][ni] = __builtin_amdgcn_mfma_f32_16x16x32_bf16(af[mi], bv[ni], acc[mi][ni], 0, 0, 0);
    }
  }

  __syncthreads();
  float csv[4], biv[4];
  #pragma unroll
  for (int ni=0;ni<4;ni++){
    const int col = n0c + wc*64 + ni*16 + (lane&15);
    csv[ni] = csum[a*HN + col];
    biv[ni] = bias[a*HN + col];
  }
  #pragma unroll
  for (int mi=0;mi<4;mi++){
    const int rl = wr*64 + mi*16 + ((lane>>4)<<2);
    #pragma unroll
    for (int v=0; v<4; ++v){
      const float2 st = stats[m0 + rl + v];
      #pragma unroll
      for (int ni=0;ni<4;ni++){
        const float o = lrelu(st.y*(acc[mi][ni][v] - st.x*csv[ni]) + biv[ni]);
        smem[(rl+v)*136 + wc*64 + ni*16 + (lane&15)] = f2bf(o);
      }
    }
  }
  __syncthreads();
  #pragma unroll
  for (int it=0; it<8; ++it){
    const int rl = it*16 + (tid>>4);
    const int ck = (tid&15)*8;
    const uint4 vv = *(const uint4*)&smem[rl*136 + ck];
    *(uint4*)(outp + (size_t)(m0+rl)*HN + n0c + ck) = vv;
  }
}

// ---------------- critic: 256x256 tile, 8-wave, 8-phase counted-vmcnt schedule ---------------
// q += (lrelu(ln([s_enc|values])@Wc1 + bc1)) . Wc2[:,argmax];  K=1024, atomicAdd f32.
__global__ __launch_bounds__(512, 2) void mfma_critic_kernel(
    const u16* __restrict__ Aa, const u16* __restrict__ Ab,
    const u16* __restrict__ Wt, const float* __restrict__ bias,
    const float2* __restrict__ stats, const float* __restrict__ csum,
    const float* __restrict__ Wc2, const float* __restrict__ bc2,
    const int* __restrict__ aip, float* __restrict__ qout)
{
  // LDS: 2 buffers x (A[256][64] 32KB + B[256][64] 32KB) = 128KB, + wc2l 16KB + ail 1KB
  __shared__ __align__(16) u16 smem[74240];
  const int tid = threadIdx.x;
  const int w = tid >> 6, lane = tid & 63;
  const int wr = w >> 2, wc = w & 3;            // 2M x 4N waves; per-wave out 128x64
  const int srow = lane >> 3, skq = (lane & 7) ^ srow;
  const int slotx = lane >> 4, lanx = lane & 7, lr = lane & 15;

  const int nwg = gridDim.x * gridDim.y;        // (2,256) = 512, %8==0
  int id = blockIdx.y * gridDim.x + blockIdx.x;
  int swz = (id & 7) * (nwg >> 3) + (id >> 3);
  const int bx = swz % gridDim.x, by = swz / gridDim.x;
  const int m0 = by * 256, n0c = bx * 256;
  const int a = m0 >> 13;
  const u16* Wbase = Wt + (size_t)a * HN * 1024;

  float* wc2l = (float*)(smem + 65536);         // [16][256] f32, ai-major
  int*   ail  = (int*)(smem + 65536 + 8192);    // [256]
  #pragma unroll
  for (int i = 0; i < 8; ++i){
    const int e = i*512 + tid;
    const int aidx = e >> 8, col = e & 255;
    wc2l[e] = Wc2[((size_t)a*HN + n0c + col)*ADN + aidx];
  }
  if (tid < 256) ail[tid] = aip[m0 + tid];

  // stage one half-tile (128 rows x 64 cols): part 0=A-lo 1=A-hi 2=B-lo 3=B-hi of K-tile tau
  auto STAGE = [&](int tau, int part){
    u16* dst = smem + (tau & 1)*32768 + ((part >> 1) ? 16384 : 0) + (part & 1)*8192 + w*1024;
    if (part < 2){
      const int k0 = tau * 64;
      const u16* asrc = (k0 < 512) ? Aa : Ab;
      const int acol = (k0 & 511) + skq*8;
      const int grow = m0 + (part & 1)*128 + w*16 + srow;
      gload16(asrc + (size_t)grow*HN + acol, dst);
      gload16(asrc + (size_t)(grow + 8)*HN + acol, dst + 512);
    } else {
      const int bcol = tau*64 + skq*8;
      const int grow = n0c + (part & 1)*128 + w*16 + srow;
      gload16(Wbase + (size_t)grow*1024 + bcol, dst);
      gload16(Wbase + (size_t)(grow + 8)*1024 + bcol, dst + 512);
    }
  };

  // prologue: tiles 0 and 1 fully staged; wait tile 0 (8 newest = tile 1 may fly)
  STAGE(0,0); STAGE(0,1); STAGE(0,2); STAGE(0,3);
  STAGE(1,0); STAGE(1,1); STAGE(1,2); STAGE(1,3);
  asm volatile("s_waitcnt vmcnt(8)" ::: "memory");
  __builtin_amdgcn_sched_barrier(0);
  __builtin_amdgcn_s_barrier();

  f32x4 acc[8][4] = {};

  #pragma unroll 1
  for (int tau = 0; tau < 16; ++tau){
    const u16* AB = smem + (tau & 1)*32768;
    const int so0 = ((0 | slotx) ^ lanx)*8;     // k-slot 0 swizzled
    const int so1 = ((4 | slotx) ^ lanx)*8;     // k-slot 1 swizzled
    bf16x8 af[4][2], bn01[2][2], bn23[2][2];

    // ---- q0: read A(m0-3)+B(n0,n1); stage A-lo(tau+1); MFMA m0-3 x n0-1
    #pragma unroll
    for (int mf = 0; mf < 4; ++mf){
      const int r = (wr*128 + mf*16 + lr)*64;
      af[mf][0] = *(const bf16x8*)&AB[r + so0];
      af[mf][1] = *(const bf16x8*)&AB[r + so1];
    }
    #pragma unroll
    for (int nf = 0; nf < 2; ++nf){
      const int r = 16384 + (wc*64 + nf*16 + lr)*64;
      bn01[nf][0] = *(const bf16x8*)&AB[r + so0];
      bn01[nf][1] = *(const bf16x8*)&AB[r + so1];
    }
    if (tau >= 1 && tau <= 14) STAGE(tau + 1, 0);
    __builtin_amdgcn_s_barrier();
    __builtin_amdgcn_s_setprio(1);
    #pragma unroll
    for (int mf = 0; mf < 4; ++mf)
      #pragma unroll
      for (int nf = 0; nf < 2; ++nf){
        acc[mf][nf] = __builtin_amdgcn_mfma_f32_16x16x32_bf16(af[mf][0], bn01[nf][0], acc[mf][nf], 0,0,0);
        acc[mf][nf] = __builtin_amdgcn_mfma_f32_16x16x32_bf16(af[mf][1], bn01[nf][1], acc[mf][nf], 0,0,0);
      }
    __builtin_amdgcn_s_setprio(0);
    __builtin_amdgcn_s_barrier();

    // ---- q1: read B(n2,n3); stage A-hi(tau+1); MFMA m0-3 x n2-3
    #pragma unroll
    for (int nf = 0; nf < 2; ++nf){
      const int r = 16384 + (wc*64 + (nf + 2)*16 + lr)*64;
      bn23[nf][0] = *(const bf16x8*)&AB[r + so0];
      bn23[nf][1] = *(const bf16x8*)&AB[r + so1];
    }
    if (tau >= 1 && tau <= 14) STAGE(tau + 1, 1);
    __builtin_amdgcn_s_barrier();
    __builtin_amdgcn_s_setprio(1);
    #pragma unroll
    for (int mf = 0; mf < 4; ++mf)
      #pragma unroll
      for (int nf = 0; nf < 2; ++nf){
        acc[mf][nf+2] = __builtin_amdgcn_mfma_f32_16x16x32_bf16(af[mf][0], bn23[nf][0], acc[mf][nf+2], 0,0,0);
        acc[mf][nf+2] = __builtin_amdgcn_mfma_f32_16x16x32_bf16(af[mf][1], bn23[nf][1], acc[mf][nf+2], 0,0,0);
      }
    __builtin_amdgcn_s_setprio(0);
    __builtin_amdgcn_s_barrier();

    // ---- q2: read A(m4-7); stage B-lo(tau+2); MFMA m4-7 x n2-3
    #pragma unroll
    for (int mf = 0; mf < 4; ++mf){
      const int r = (wr*128 + (mf + 4)*16 + lr)*64;
      af[mf][0] = *(const bf16x8*)&AB[r + so0];
      af[mf][1] = *(const bf16x8*)&AB[r + so1];
    }
    if (tau <= 13) STAGE(tau + 2, 2);
    __builtin_amdgcn_s_barrier();
    __builtin_amdgcn_s_setprio(1);
    #pragma unroll
    for (int mf = 0; mf < 4; ++mf)
      #pragma unroll
      for (int nf = 0; nf < 2; ++nf){
        acc[mf+4][nf+2] = __builtin_amdgcn_mfma_f32_16x16x32_bf16(af[mf][0], bn23[nf][0], acc[mf+4][nf+2], 0,0,0);
        acc[mf+4][nf+2] = __builtin_amdgcn_mfma_f32_16x16x32_bf16(af[mf][1], bn23[nf][1], acc[mf+4][nf+2], 0,0,0);
      }
    __builtin_amdgcn_s_setprio(0);
    __builtin_amdgcn_s_barrier();

    // ---- q3: stage B-hi(tau+2); MFMA m4-7 x n0-1 (regs only)
    if (tau <= 13) STAGE(tau + 2, 3);
    __builtin_amdgcn_s_barrier();
    __builtin_amdgcn_s_setprio(1);
    #pragma unroll
    for (int mf = 0; mf < 4; ++mf)
      #pragma unroll
      for (int nf = 0; nf < 2; ++nf){
        acc[mf+4][nf] = __builtin_amdgcn_mfma_f32_16x16x32_bf16(af[mf][0], bn01[nf][0], acc[mf+4][nf], 0,0,0);
        acc[mf+4][nf] = __builtin_amdgcn_mfma_f32_16x16x32_bf16(af[mf][1], bn01[nf][1], acc[mf+4][nf], 0,0,0);
      }
    __builtin_amdgcn_s_setprio(0);

    // ---- K-tile boundary: counted vmcnt (A(tau+1) landed; B(tau+2) may fly), then barrier
    if (tau < 14)       { asm volatile("s_waitcnt vmcnt(4)" ::: "memory"); }
    else if (tau == 14) { asm volatile("s_waitcnt vmcnt(0)" ::: "memory"); }
    __builtin_amdgcn_sched_barrier(0);
    __builtin_amdgcn_s_barrier();
    __builtin_amdgcn_sched_barrier(0);
  }

  // ---- epilogue: LN-fold + lrelu + fused q-dot against Wc2[:,argmax]
  float csv[4], biv[4];
  #pragma unroll
  for (int nf = 0; nf < 4; ++nf){
    const int col = n0c + wc*64 + nf*16 + lr;
    csv[nf] = csum[a*HN + col];
    biv[nf] = bias[a*HN + col];
  }
  #pragma unroll
  for (int mf = 0; mf < 8; ++mf){
    const int rbase = wr*128 + mf*16 + slotx*4;
    #pragma unroll
    for (int v = 0; v < 4; ++v){
      const int rl = rbase + v;
      const float2 st = stats[m0 + rl];
      const int aidx = ail[rl];
      float p = 0.f;
      #pragma unroll
      for (int nf = 0; nf < 4; ++nf){
        const float o = lrelu(st.y*(acc[mf][nf][v] - st.x*csv[nf]) + biv[nf]);
        p = fmaf(o, wc2l[aidx*256 + wc*64 + nf*16 + lr], p);
      }
      p += __shfl_xor(p,1); p += __shfl_xor(p,2);
      p += __shfl_xor(p,4); p += __shfl_xor(p,8);
      if (lr == 0){
        if (n0c == 0 && wc == 0) p += bc2[a*ADN + aidx];
        atomicAdd(qout + m0 + rl, p);
      }
    }
  }
}

// ---------------- MFMA proj (one head): N=128 per t-block, K=512 -> kvs[t][b][agent][d] ------
__global__ __launch_bounds__(256) void mfma_proj_kernel(
    const u16* __restrict__ sa_enc, const u16* __restrict__ Wt_p,
    const float* __restrict__ bsel, u16* __restrict__ kvs, int head)
{
  __shared__ __align__(16) u16 smem[17408];
  u16* As = smem;
  u16* Bs = smem + 8192;
  const int tid = threadIdx.x;
  const int w = tid>>6, lane = tid&63;
  const int wr = w>>1, wc = w&1;
  const int srow = lane>>3, skq = (lane&7)^srow;

  const int nwg = gridDim.x * gridDim.y;              // (3, 512) = 1536, %8==0
  int id = blockIdx.y * gridDim.x + blockIdx.x;
  int swz = (id & 7) * (nwg >> 3) + (id >> 3);
  const int t = swz % gridDim.x;
  const int m0 = (swz / gridDim.x) * 128;

  const u16* Wbase = Wt_p + (size_t)(head*3 + t)*DN*HN;
  const int slotbase = (lane>>4) ^ (lane&7);
  f32x4 acc[4][4] = {};

  for (int k0 = 0; k0 < HN; k0 += 64){
    __syncthreads();
    #pragma unroll
    for (int tt=0;tt<4;tt++){
      const int rr = w*32 + tt*8;
      gload16(sa_enc + (size_t)(m0 + rr + srow)*HN + k0 + skq*8, As + rr*64);
      gload16(Wbase  + (size_t)(rr + srow)*HN      + k0 + skq*8, Bs + rr*64);
    }
    __syncthreads();
    #pragma unroll
    for (int ks=0; ks<2; ++ks){
      bf16x8 af[4], bv[4];
      const int so = ((slotbase ^ (ks<<2)))*8;
      #pragma unroll
      for (int mi=0;mi<4;mi++) af[mi] = *(const bf16x8*)&As[(wr*64+mi*16+(lane&15))*64 + so];
      #pragma unroll
      for (int ni=0;ni<4;ni++) bv[ni] = *(const bf16x8*)&Bs[(wc*64+ni*16+(lane&15))*64 + so];
      #pragma unroll
      for (int mi=0;mi<4;mi++)
        #pragma unroll
        for (int ni=0;ni<4;ni++)
          acc[mi][ni] = __builtin_amdgcn_mfma_f32_16x16x32_bf16(af[mi], bv[ni], acc[mi][ni], 0, 0, 0);
    }
  }

  __syncthreads();
  const bool issel = (t == 2);
  float biv[4];
  #pragma unroll
  for (int ni=0;ni<4;ni++){
    const int col = wc*64 + ni*16 + (lane&15);
    biv[ni] = issel ? bsel[head*DN + col] : 0.f;
  }
  #pragma unroll
  for (int mi=0;mi<4;mi++){
    const int rl = wr*64 + mi*16 + ((lane>>4)<<2);
    #pragma unroll
    for (int v=0; v<4; ++v){
      #pragma unroll
      for (int ni=0;ni<4;ni++){
        float o = acc[mi][ni][v] + biv[ni];
        if (issel) o = lrelu(o);
        smem[(rl+v)*136 + wc*64 + ni*16 + (lane&15)] = f2bf(o);
      }
    }
  }
  __syncthreads();
  #pragma unroll
  for (int it=0; it<8; ++it){
    const int rl = it*16 + (tid>>4);
    const int ck = (tid&15)*8;
    const int r = m0 + rl;
    const int ar = r >> 13, b = r & (BNB-1);
    const uint4 vv = *(const uint4*)&smem[rl*136 + ck];
    *(uint4*)(kvs + (((size_t)t*BNB + b)*AN + ar)*DN + ck) = vv;
  }
}

// ---------------- attention for ONE head: one wave per b ------------------------------------
__global__ __launch_bounds__(256) void attn_kernel(
    const u16* __restrict__ kvs, u16* __restrict__ values, int kh)
{
  __shared__ float lds[4][3232];
  const int lane = threadIdx.x & 63;
  const int wv   = threadIdx.x >> 6;
  float* selL = &lds[wv][0];
  float* keyL = &lds[wv][1056];
  float* valL = &lds[wv][2112];
  float* wL   = &lds[wv][3168];
  const int b = blockIdx.x*4 + wv;

  #pragma unroll
  for (int m=0;m<3;m++){
    const int t = (m==0) ? 2 : ((m==1) ? 0 : 1);
    float* dst = (m==0) ? selL : ((m==1) ? keyL : valL);
    const uint2* p = (const uint2*)(kvs + ((size_t)t*BNB + b)*(AN*DN));
    #pragma unroll
    for (int it=0; it<4; it++){
      uint2 u = p[it*64 + lane];
      int e = (it*64 + lane)*4;
      int j = e >> 7, d = e & 127;
      float4 f;
      f.x = bflo(u.x); f.y = bfhi(u.x); f.z = bflo(u.y); f.w = bfhi(u.y);
      *(float4*)&dst[j*132 + d] = f;
    }
  }
  __syncthreads();

  const int i = lane >> 3, j = lane & 7;
  float acc = 0.f;
  #pragma unroll 8
  for (int dq=0; dq<32; dq++){
    const float4 s4 = *(const float4*)&selL[i*132 + dq*4];
    const float4 k4 = *(const float4*)&keyL[j*132 + dq*4];
    acc += s4.x*k4.x + s4.y*k4.y + s4.z*k4.z + s4.w*k4.w;
  }
  float logit = acc * 0.08838834764831845f;
  if (i == j) logit = -INFINITY;
  float mx = logit;
  mx = fmaxf(mx, __shfl_xor(mx,1,8));
  mx = fmaxf(mx, __shfl_xor(mx,2,8));
  mx = fmaxf(mx, __shfl_xor(mx,4,8));
  const float e = __expf(logit - mx);
  float s = e;
  s += __shfl_xor(s,1,8);
  s += __shfl_xor(s,2,8);
  s += __shfl_xor(s,4,8);
  wL[i*8 + j] = e / s;
  __syncthreads();

  const int dq = lane & 7;
  float4 o[4];
  #pragma unroll
  for (int tt=0;tt<4;tt++) o[tt] = make_float4(0.f,0.f,0.f,0.f);
  #pragma unroll
  for (int jj=0;jj<8;jj++){
    const float wj = wL[i*8 + jj];
    #pragma unroll
    for (int tt=0;tt<4;tt++){
      const float4 v4 = *(const float4*)&valL[jj*132 + tt*32 + dq*4];
      o[tt].x += wj*v4.x; o[tt].y += wj*v4.y; o[tt].z += wj*v4.z; o[tt].w += wj*v4.w;
    }
  }
  u16* dst = values + ((size_t)i*BNB + b)*HN + kh*DN;
  #pragma unroll
  for (int tt=0;tt<4;tt++)
    *(ushort4*)(dst + tt*32 + dq*4) = f4bf(o[tt]);
}

// ---------------- per-row stats of cin = concat(s_enc, values) (1024), bf16 inputs -----------
__global__ __launch_bounds__(256) void stats_cin_kernel(
    const u16* __restrict__ s_enc, const u16* __restrict__ values, float2* __restrict__ st)
{
  const int lane = threadIdx.x & 63;
  const int r = blockIdx.x*4 + (threadIdx.x >> 6);
  const uint4* p1 = (const uint4*)(s_enc + (size_t)r*HN);
  const uint4* p2 = (const uint4*)(values + (size_t)r*HN);
  uint4 va = p1[lane];
  uint4 vb = p2[lane];
  float s=0.f, q=0.f;
  const unsigned wa[4] = {va.x, va.y, va.z, va.w};
  const unsigned wb[4] = {vb.x, vb.y, vb.z, vb.w};
  #pragma unroll
  for (int t=0;t<4;t++){
    float f0 = bflo(wa[t]), f1 = bfhi(wa[t]);
    float g0 = bflo(wb[t]), g1 = bfhi(wb[t]);
    s += f0+f1+g0+g1; q += f0*f0+f1*f1+g0*g0+g1*g1;
  }
  #pragma unroll
  for (int off=32; off; off>>=1){ s += __shfl_xor(s,off); q += __shfl_xor(q,off); }
  if (lane==0){
    float m = s*(1.f/1024.f); float v = fmaxf(q*(1.f/1024.f) - m*m, 0.f);
    st[r] = make_float2(m, rsqrtf(v + 1e-5f));
  }
}

extern "C" void kernel_launch(void* const* d_in, const int* in_sizes, int n_in,
                              void* d_out, int out_size, void* d_ws, size_t ws_size,
                              hipStream_t stream)
{
  (void)in_sizes; (void)n_in; (void)ws_size;
  const float* states  = (const float*)d_in[0];
  const float* actions = (const float*)d_in[1];
  const float* Ws_s    = (const float*)d_in[2];
  const float* bs_s    = (const float*)d_in[3];
  const float* Ws_sa   = (const float*)d_in[4];
  const float* bs_sa   = (const float*)d_in[5];
  const float* Wk      = (const float*)d_in[6];
  const float* Wv      = (const float*)d_in[7];
  const float* Wsel    = (const float*)d_in[8];
  const float* bsel    = (const float*)d_in[9];
  const float* Wc1     = (const float*)d_in[10];
  const float* bc1     = (const float*)d_in[11];
  const float* Wc2     = (const float*)d_in[12];
  const float* bc2     = (const float*)d_in[13];
  float* outp = (float*)d_out;

  char* ws = (char*)d_ws;
  size_t off = 0;
  auto alloc = [&](size_t n){ void* p = ws + off; off += (n + 255) & ~(size_t)255; return p; };
  u16*    slot1  = (u16*)   alloc((size_t)AN*BNB*HN*2);   // 64 MB: kvs during attn loop, s_enc after
  u16*    s_enc  = slot1;
  u16*    kvs    = slot1;                                  // 48 MB <= 64 MB
  u16*    sa_enc = (u16*)   alloc((size_t)AN*BNB*HN*2);   // 64 MB
  u16*    values = (u16*)   alloc((size_t)AN*BNB*HN*2);   // 64 MB
  u16*    sa_bf  = (u16*)   alloc((size_t)AN*BNB*192*2);  // 24 MB
  u16*    Wt_s   = (u16*)   alloc((size_t)AN*HN*128*2);
  u16*    Wt_sa  = (u16*)   alloc((size_t)AN*HN*192*2);
  u16*    Wt_c1  = (u16*)   alloc((size_t)AN*HN*1024*2);
  u16*    Wt_p   = (u16*)   alloc((size_t)NHEADS*3*DN*HN*2);
  float2* st_s   = (float2*)alloc((size_t)AN*BNB*8);
  float2* st_sa  = (float2*)alloc((size_t)AN*BNB*8);
  float2* st_cin = (float2*)alloc((size_t)AN*BNB*8);
  float*  cs_s   = (float*) alloc((size_t)AN*HN*4);
  float*  cs_sa  = (float*) alloc((size_t)AN*HN*4);
  float*  cs_c1  = (float*) alloc((size_t)AN*HN*4);
  int*    aip    = (int*)   alloc((size_t)AN*BNB*4);

  hipMemsetAsync(d_out, 0, (size_t)out_size*4, stream);
  prep_kernel<<<dim3(AN*BNB/4), 256, 0, stream>>>(states, actions, sa_bf, st_s, st_sa, aip);
  transw_all_kernel<<<dim3(6144), dim3(32,8), 0, stream>>>(
      Ws_s, Ws_sa, Wc1, Wk, Wv, Wsel, Wt_s, Wt_sa, Wt_c1, Wt_p);
  colsum_bf_kernel<<<dim3(3*AN*HN/4), 256, 0, stream>>>(Wt_s, Wt_sa, Wt_c1, cs_s, cs_sa, cs_c1);

  mfma_enc_kernel<1><<<dim3(4,512), 256, 0, stream>>>(sa_bf, Wt_sa, bs_sa, st_sa, cs_sa, sa_enc);
  for (int kh = 0; kh < NHEADS; ++kh){
    mfma_proj_kernel<<<dim3(3,512), 256, 0, stream>>>(sa_enc, Wt_p, bsel, kvs, kh);
    attn_kernel<<<dim3(BNB/4), 256, 0, stream>>>(kvs, values, kh);
  }
  mfma_enc_kernel<0><<<dim3(4,512), 256, 0, stream>>>(sa_bf, Wt_s, bs_s, st_s, cs_s, s_enc);
  stats_cin_kernel<<<dim3(AN*BNB/4), 256, 0, stream>>>(s_enc, values, st_cin);
  mfma_critic_kernel<<<dim3(2,256), 512, 0, stream>>>(s_enc, values, Wt_c1, bc1, st_cin, cs_c1,
                                                      Wc2, bc2, aip, outp);
}